// Round 2
// baseline (1002.587 us; speedup 1.0000x reference)
//
#include <hip/hip_runtime.h>

#define B_  2
#define S_  2048
#define D_  1024
#define H_  16
#define DH_ 64

typedef _Float16 f16x8 __attribute__((ext_vector_type(8)));
typedef _Float16 f16x4 __attribute__((ext_vector_type(4)));
typedef float    f32x4 __attribute__((ext_vector_type(4)));

#define MFMA16(a, b, c) __builtin_amdgcn_mfma_f32_16x16x32_f16((a), (b), (c), 0, 0, 0)

// width-16 async global->LDS (LDS dest is wave-uniform base + lane*16)
#define GLD16(gptr, lptr)                                                           \
    __builtin_amdgcn_global_load_lds(                                               \
        (const __attribute__((address_space(1))) void*)(gptr),                      \
        (__attribute__((address_space(3))) void*)(lptr), 16, 0, 0)

// ---------------------------------------------------------------------------
// Prep 1: fp32 -> fp16 elementwise for q_in/k_in/v_in (layout preserved).
// ---------------------------------------------------------------------------
__global__ __launch_bounds__(256) void cvt_x(
    const float* __restrict__ q, const float* __restrict__ k, const float* __restrict__ v,
    _Float16* __restrict__ x16)
{
    const int z = blockIdx.y;
    const float* src = (z == 0) ? q : (z == 1) ? k : v;
    _Float16* dst = x16 + (size_t)z * (4096 * 1024);
    const size_t i = ((size_t)blockIdx.x * 256 + threadIdx.x) * 8;
    float4 a = *(const float4*)(src + i);
    float4 b = *(const float4*)(src + i + 4);
    f16x8 o = { (_Float16)a.x, (_Float16)a.y, (_Float16)a.z, (_Float16)a.w,
                (_Float16)b.x, (_Float16)b.y, (_Float16)b.z, (_Float16)b.w };
    *(f16x8*)(dst + i) = o;
}

// ---------------------------------------------------------------------------
// Prep 2: convert + transpose weights: Wt[n][k] = (fp16)W[k][n].  64x64 tiles.
// ---------------------------------------------------------------------------
__global__ __launch_bounds__(256) void cvt_w(
    const float* __restrict__ Wq, const float* __restrict__ Wk,
    const float* __restrict__ Wv, const float* __restrict__ Wo,
    _Float16* __restrict__ Wt3, _Float16* __restrict__ Wot)
{
    const int z = blockIdx.z;
    const float* W = (z == 0) ? Wq : (z == 1) ? Wk : (z == 2) ? Wv : Wo;
    _Float16* Wt = (z < 3) ? (Wt3 + (size_t)z * (1024 * 1024)) : Wot;

    __shared__ _Float16 T[64][72];
    const int k0 = blockIdx.y * 64, n0 = blockIdx.x * 64;
    const int r = threadIdx.x >> 3, c8 = (threadIdx.x & 7) * 8;

#pragma unroll
    for (int it = 0; it < 2; ++it) {
        const int row = it * 32 + r;
        const float* p = W + (size_t)(k0 + row) * D_ + n0 + c8;
        float4 a = *(const float4*)p;
        float4 b = *(const float4*)(p + 4);
        _Float16* t = &T[row][c8];
        t[0] = (_Float16)a.x; t[1] = (_Float16)a.y; t[2] = (_Float16)a.z; t[3] = (_Float16)a.w;
        t[4] = (_Float16)b.x; t[5] = (_Float16)b.y; t[6] = (_Float16)b.z; t[7] = (_Float16)b.w;
    }
    __syncthreads();
#pragma unroll
    for (int it = 0; it < 2; ++it) {
        const int nrow = it * 32 + r;
        f16x8 o = { T[c8 + 0][nrow], T[c8 + 1][nrow], T[c8 + 2][nrow], T[c8 + 3][nrow],
                    T[c8 + 4][nrow], T[c8 + 5][nrow], T[c8 + 6][nrow], T[c8 + 7][nrow] };
        *(f16x8*)(Wt + (size_t)(n0 + nrow) * D_ + k0 + c8) = o;
    }
}

// ---------------------------------------------------------------------------
// QKV GEMM (m97 structure). Epilogue writes attention-ready layouts:
//   z==0: Qh[bh][s][dh]                       (plain)
//   z==1: Kh[bh][s][dh ^ ((s&7)*8)]           (XOR-swizzled rows)
//   z==2: Vt[bh][dh][(s&~63) + ((s&63)^((dh&7)*8))]   (transposed + swizzled)
// ---------------------------------------------------------------------------
__global__ __launch_bounds__(256) void gemm_qkv_f(
    const _Float16* __restrict__ X16, const _Float16* __restrict__ Wt3,
    const float* __restrict__ bq, const float* __restrict__ bk, const float* __restrict__ bv,
    _Float16* __restrict__ QKVh)
{
    const int z = blockIdx.z;
    const _Float16* Ag = X16 + (size_t)z * (4096 * 1024);
    const _Float16* Bg = Wt3 + (size_t)z * (1024 * 1024);
    const float* bias = (z == 0) ? bq : (z == 1) ? bk : bv;
    _Float16* dst = QKVh + (size_t)z * (4096 * 1024);

    __shared__ _Float16 As[128 * 32];
    __shared__ _Float16 Bs[128 * 32];

    const int tid = threadIdx.x, lane = tid & 63, wave = tid >> 6;
    const int quad = lane >> 4, col = lane & 15;
    const int wm = wave >> 1, wn = wave & 1;
    const int bm0 = blockIdx.y * 128, bn0 = blockIdx.x * 128;

    const int srow = lane >> 2;
    const int ska  = (lane & 3) * 8;

    f32x4 acc[4][4] = {};

    for (int k0 = 0; k0 < D_; k0 += 32) {
#pragma unroll
        for (int i = 0; i < 2; ++i) {
            const int ch = wave * 2 + i;
            const int row = ch * 16 + srow;
            GLD16(Ag + (size_t)(bm0 + row) * D_ + k0 + ska, &As[ch * 512]);
            GLD16(Bg + (size_t)(bn0 + row) * D_ + k0 + ska, &Bs[ch * 512]);
        }
        __syncthreads();

        f16x8 a[4], b[4];
#pragma unroll
        for (int r = 0; r < 4; ++r)
            a[r] = *(const f16x8*)&As[(wm * 64 + r * 16 + col) * 32 + quad * 8];
#pragma unroll
        for (int c = 0; c < 4; ++c)
            b[c] = *(const f16x8*)&Bs[(wn * 64 + c * 16 + col) * 32 + quad * 8];
#pragma unroll
        for (int r = 0; r < 4; ++r)
#pragma unroll
            for (int c = 0; c < 4; ++c)
                acc[r][c] = MFMA16(a[r], b[c], acc[r][c]);
        __syncthreads();
    }

    if (z == 2) {
        // V: transposed + swizzled, packed 4-half stores (e runs along s)
#pragma unroll
        for (int r = 0; r < 4; ++r)
#pragma unroll
            for (int c = 0; c < 4; ++c) {
                const int n = bn0 + wn * 64 + c * 16 + col;
                const int h = n >> 6, dh = n & 63;
                const float bi = bias[n];
                const int m0 = bm0 + wm * 64 + r * 16 + quad * 4;
                const int bb = m0 >> 11, s0 = m0 & 2047;
                f16x4 pk = { (_Float16)(acc[r][c][0] + bi), (_Float16)(acc[r][c][1] + bi),
                             (_Float16)(acc[r][c][2] + bi), (_Float16)(acc[r][c][3] + bi) };
                const int kin = (s0 & ~63) + ((s0 & 63) ^ ((dh & 7) * 8));
                *(f16x4*)(dst + ((size_t)(bb * H_ + h) * DH_ + dh) * S_ + kin) = pk;
            }
    } else if (z == 1) {
#pragma unroll
        for (int r = 0; r < 4; ++r)
#pragma unroll
            for (int c = 0; c < 4; ++c) {
                const int n = bn0 + wn * 64 + c * 16 + col;
                const int h = n >> 6, dh = n & 63;
                const float bi = bias[n];
#pragma unroll
                for (int e = 0; e < 4; ++e) {
                    const int m = bm0 + wm * 64 + r * 16 + quad * 4 + e;
                    const int bb = m >> 11, s = m & 2047;
                    dst[(((size_t)(bb * H_ + h)) * S_ + s) * DH_ + (dh ^ ((s & 7) * 8))] =
                        (_Float16)(acc[r][c][e] + bi);
                }
            }
    } else {
#pragma unroll
        for (int r = 0; r < 4; ++r)
#pragma unroll
            for (int c = 0; c < 4; ++c) {
                const int n = bn0 + wn * 64 + c * 16 + col;
                const int h = n >> 6, dh = n & 63;
                const float bi = bias[n];
#pragma unroll
                for (int e = 0; e < 4; ++e) {
                    const int m = bm0 + wm * 64 + r * 16 + quad * 4 + e;
                    const int bb = m >> 11, s = m & 2047;
                    dst[(((size_t)(bb * H_ + h)) * S_ + s) * DH_ + dh] =
                        (_Float16)(acc[r][c][e] + bi);
                }
            }
    }
}

__global__ __launch_bounds__(256) void gemm_out_f(
    const _Float16* __restrict__ Ag, const _Float16* __restrict__ Bg,
    const float* __restrict__ bias, float* __restrict__ out)
{
    __shared__ _Float16 As[128 * 32];
    __shared__ _Float16 Bs[128 * 32];

    const int tid = threadIdx.x, lane = tid & 63, wave = tid >> 6;
    const int quad = lane >> 4, col = lane & 15;
    const int wm = wave >> 1, wn = wave & 1;
    const int bm0 = blockIdx.y * 128, bn0 = blockIdx.x * 128;

    const int srow = lane >> 2;
    const int ska  = (lane & 3) * 8;

    f32x4 acc[4][4] = {};

    for (int k0 = 0; k0 < D_; k0 += 32) {
#pragma unroll
        for (int i = 0; i < 2; ++i) {
            const int ch = wave * 2 + i;
            const int row = ch * 16 + srow;
            GLD16(Ag + (size_t)(bm0 + row) * D_ + k0 + ska, &As[ch * 512]);
            GLD16(Bg + (size_t)(bn0 + row) * D_ + k0 + ska, &Bs[ch * 512]);
        }
        __syncthreads();

        f16x8 a[4], b[4];
#pragma unroll
        for (int r = 0; r < 4; ++r)
            a[r] = *(const f16x8*)&As[(wm * 64 + r * 16 + col) * 32 + quad * 8];
#pragma unroll
        for (int c = 0; c < 4; ++c)
            b[c] = *(const f16x8*)&Bs[(wn * 64 + c * 16 + col) * 32 + quad * 8];
#pragma unroll
        for (int r = 0; r < 4; ++r)
#pragma unroll
            for (int c = 0; c < 4; ++c)
                acc[r][c] = MFMA16(a[r], b[c], acc[r][c]);
        __syncthreads();
    }

#pragma unroll
    for (int r = 0; r < 4; ++r)
#pragma unroll
        for (int c = 0; c < 4; ++c) {
            const int n = bn0 + wn * 64 + c * 16 + col;
            const float bi = bias[n];
#pragma unroll
            for (int e = 0; e < 4; ++e) {
                const int m = bm0 + wm * 64 + r * 16 + quad * 4 + e;
                out[(size_t)m * D_ + n] = acc[r][c][e] + bi;
            }
        }
}

// ---------------------------------------------------------------------------
// Attention. KT=64 per barrier. K and V staged via global_load_lds into
// LINEAR LDS (no write conflicts); fragment reads apply the matching XOR
// swizzle (2-way max = free). Pass-1 does one combined (m,l) update per 64
// keys; pass-2 folds 1/l into the exponent.
// ---------------------------------------------------------------------------
__global__ __launch_bounds__(256) void attn_kernel(
    const _Float16* __restrict__ Qh, const _Float16* __restrict__ Kh,
    const _Float16* __restrict__ Vt, const float* __restrict__ mask,
    float* __restrict__ attn, _Float16* __restrict__ ctx)
{
    const int bh = blockIdx.y;
    const int b = bh >> 4, h = bh & 15;
    const int qb0 = blockIdx.x * 64;
    const int tid = threadIdx.x, lane = tid & 63, wave = tid >> 6;
    const int quad = lane >> 4, col = lane & 15;

    __shared__ __align__(16) _Float16 Ks[64 * 64];      // [k_local][dh'] linear
    __shared__ __align__(16) _Float16 Vs[64 * 64];      // [dh][k_local'] linear
    __shared__ __align__(16) _Float16 Ps[4][16][72];    // per-wave P, padded

    const int qrow0 = qb0 + wave * 16;

    const _Float16* qp = Qh + ((size_t)bh * S_ + qrow0 + col) * DH_;
    const f16x8 aq0 = *(const f16x8*)(qp + quad * 8);
    const f16x8 aq1 = *(const f16x8*)(qp + 32 + quad * 8);

    const float LOG2E = 1.4426950408889634f;
    const float scale_l2 = 0.125f * LOG2E;

    float mrow[4] = { -1e30f, -1e30f, -1e30f, -1e30f };
    float lrow[4] = { 0.f, 0.f, 0.f, 0.f };

    // staging roles: per GLD16 round a wave covers 8 rows of 128B
    const int srow = lane >> 3;          // 0..7
    const int sb   = (lane & 7) * 8;     // half offset within row

    // ---------------- pass 1: row max & sum (base-2 domain) ----------------
    for (int kt = 0; kt < S_; kt += 64) {
#pragma unroll
        for (int r = 0; r < 2; ++r) {
            const int row0 = r * 32 + wave * 8;
            GLD16(Kh + ((size_t)bh * S_ + kt + row0 + srow) * DH_ + sb, &Ks[row0 * DH_]);
        }
        __syncthreads();

        float s2a[4][4];
#pragma unroll
        for (int c = 0; c < 4; ++c) {
            const int rk = c * 16 + col;
            const int kx = (quad * 8) ^ ((rk & 7) * 8);
            f16x8 b0 = *(const f16x8*)&Ks[rk * 64 + kx];
            f16x8 b1 = *(const f16x8*)&Ks[rk * 64 + (kx ^ 32)];
            f32x4 sc = {};
            sc = MFMA16(aq0, b0, sc);
            sc = MFMA16(aq1, b1, sc);
#pragma unroll
            for (int e = 0; e < 4; ++e) {
                const int q = qrow0 + quad * 4 + e;
                s2a[c][e] = sc[e] * scale_l2 +
                    mask[((size_t)b * S_ + q) * S_ + kt + rk] * LOG2E;
            }
        }
#pragma unroll
        for (int e = 0; e < 4; ++e) {
            float nm = fmaxf(fmaxf(mrow[e], s2a[0][e]), fmaxf(s2a[1][e], s2a[2][e]));
            nm = fmaxf(nm, s2a[3][e]);
            lrow[e] = lrow[e] * exp2f(mrow[e] - nm)
                    + exp2f(s2a[0][e] - nm) + exp2f(s2a[1][e] - nm)
                    + exp2f(s2a[2][e] - nm) + exp2f(s2a[3][e] - nm);
            mrow[e] = nm;
        }
        __syncthreads();
    }

    // merge (m,l) across the 16 lanes (cols) holding each row
#pragma unroll
    for (int off = 1; off < 16; off <<= 1) {
#pragma unroll
        for (int e = 0; e < 4; ++e) {
            const float om = __shfl_xor(mrow[e], off, 64);
            const float ol = __shfl_xor(lrow[e], off, 64);
            const float nm = fmaxf(mrow[e], om);
            lrow[e] = lrow[e] * exp2f(mrow[e] - nm) + ol * exp2f(om - nm);
            mrow[e] = nm;
        }
    }
    float moff[4];
#pragma unroll
    for (int e = 0; e < 4; ++e) moff[e] = mrow[e] + log2f(lrow[e]);

    // ---------------- pass 2: attn write + PV ----------------
    f32x4 cacc[4] = {};
    for (int kt = 0; kt < S_; kt += 64) {
#pragma unroll
        for (int r = 0; r < 2; ++r) {
            const int row0 = r * 32 + wave * 8;
            GLD16(Kh + ((size_t)bh * S_ + kt + row0 + srow) * DH_ + sb, &Ks[row0 * DH_]);
            GLD16(Vt + ((size_t)bh * DH_ + row0 + srow) * S_ + kt + sb, &Vs[row0 * DH_]);
        }
        __syncthreads();

#pragma unroll
        for (int c = 0; c < 4; ++c) {
            const int rk = c * 16 + col;
            const int kx = (quad * 8) ^ ((rk & 7) * 8);
            f16x8 b0 = *(const f16x8*)&Ks[rk * 64 + kx];
            f16x8 b1 = *(const f16x8*)&Ks[rk * 64 + (kx ^ 32)];
            f32x4 sc = {};
            sc = MFMA16(aq0, b0, sc);
            sc = MFMA16(aq1, b1, sc);
#pragma unroll
            for (int e = 0; e < 4; ++e) {
                const int q = qrow0 + quad * 4 + e;
                const float p = exp2f(sc[e] * scale_l2 +
                    mask[((size_t)b * S_ + q) * S_ + kt + rk] * LOG2E - moff[e]);
                attn[((size_t)bh * S_ + q) * S_ + kt + rk] = p;
                Ps[wave][quad * 4 + e][rk] = (_Float16)p;
            }
        }

        // PV: A = P (16x64 in 2 k-steps), B = V tiles (swizzled reads)
#pragma unroll
        for (int ks = 0; ks < 2; ++ks) {
            f16x8 ap = *(const f16x8*)&Ps[wave][col][ks * 32 + quad * 8];
#pragma unroll
            for (int nt = 0; nt < 4; ++nt) {
                const int rd = nt * 16 + col;
                const int vx = (ks * 32 + quad * 8) ^ ((rd & 7) * 8);
                f16x8 bv = *(const f16x8*)&Vs[rd * 64 + vx];
                cacc[nt] = MFMA16(ap, bv, cacc[nt]);
            }
        }
        __syncthreads();
    }

    // write ctx (merge heads): [b][s][h*64+dh], fp16
#pragma unroll
    for (int nt = 0; nt < 4; ++nt)
#pragma unroll
        for (int e = 0; e < 4; ++e) {
            const int s = qrow0 + quad * 4 + e;
            const int d = h * DH_ + nt * 16 + col;
            ctx[((size_t)b * S_ + s) * D_ + d] = (_Float16)cacc[nt][e];
        }
}

extern "C" void kernel_launch(void* const* d_in, const int* in_sizes, int n_in,
                              void* d_out, int out_size, void* d_ws, size_t ws_size,
                              hipStream_t stream) {
    const float* q_in = (const float*)d_in[0];
    const float* k_in = (const float*)d_in[1];
    const float* v_in = (const float*)d_in[2];
    const float* mask = (const float*)d_in[3];
    const float* Wq   = (const float*)d_in[4];
    const float* bq   = (const float*)d_in[5];
    const float* Wk   = (const float*)d_in[6];
    const float* bk   = (const float*)d_in[7];
    const float* Wv   = (const float*)d_in[8];
    const float* bv   = (const float*)d_in[9];
    const float* Wo   = (const float*)d_in[10];
    const float* bo   = (const float*)d_in[11];

    float* out  = (float*)d_out;
    float* attn = out + (size_t)B_ * S_ * D_;

    const size_t elems = (size_t)B_ * H_ * S_ * DH_;   // 4,194,304

    _Float16* Qh  = (_Float16*)d_ws;
    _Float16* Kh  = Qh + elems;        // swizzled [bh][s][dh']
    _Float16* Vh  = Kh + elems;        // transposed [bh][dh][s']
    _Float16* Ctx = Vh + elems;
    _Float16* Wot = Ctx + elems;

    _Float16* X16 = (_Float16*)attn;   // scratch inside attn output region
    _Float16* Wt3 = X16 + 3 * elems;

    cvt_x<<<dim3(2048, 3), 256, 0, stream>>>(q_in, k_in, v_in, X16);
    cvt_w<<<dim3(16, 16, 4), 256, 0, stream>>>(Wq, Wk, Wv, Wo, Wt3, Wot);
    gemm_qkv_f<<<dim3(8, 32, 3), 256, 0, stream>>>(X16, Wt3, bq, bk, bv, Qh);
    attn_kernel<<<dim3(32, 32), 256, 0, stream>>>(Qh, Kh, Vh, mask, attn, Ctx);
    gemm_out_f<<<dim3(8, 32), 256, 0, stream>>>(Ctx, Wot, bo, out);
}